// Round 10
// baseline (418.312 us; speedup 1.0000x reference)
//
#include <hip/hip_runtime.h>
#include <math.h>
#include <float.h>

#define NROWS 131072
#define SDIM 64
#define HDIM 128
#define KCODES 512
#define ADIM 8

#define XSTR 68    // xT/inT stride: 68%4==0 (b128 aligned), 2-way banks max
#define WSTR 132   // weight-chunk stride
#define ESTR 264   // e-panel stride (256 codes + 8 pad)

// ===========================================================================
// prep: eT[j][c] = emb[c][j]  (256 KB) j-major for coalesced panel staging.
// ===========================================================================
__global__ void prep_e_kernel(const float* __restrict__ emb, float* __restrict__ eT) {
    int g = blockIdx.x * 256 + threadIdx.x;        // 0..16383
    int c = g >> 5, j4 = g & 31;
    float4 v = ((const float4*)emb)[(size_t)c * 32 + j4];
    eT[(size_t)(4 * j4 + 0) * KCODES + c] = v.x;
    eT[(size_t)(4 * j4 + 1) * KCODES + c] = v.y;
    eT[(size_t)(4 * j4 + 2) * KCODES + c] = v.z;
    eT[(size_t)(4 * j4 + 3) * KCODES + c] = v.w;
}

// ee[k] = sum_j emb[k][j]^2 — exact FP chain from rounds 1-9 (absmax 0.0)
__global__ void ee_kernel(const float* __restrict__ emb, float* __restrict__ ee) {
    int k = blockIdx.x * blockDim.x + threadIdx.x;
    if (k >= KCODES) return;
    const float* e = emb + k * HDIM;
    float a0 = 0.f, a1 = 0.f, a2 = 0.f, a3 = 0.f;
#pragma unroll
    for (int j = 0; j < HDIM; j += 4) {
        a0 = fmaf(e[j + 0], e[j + 0], a0);
        a1 = fmaf(e[j + 1], e[j + 1], a1);
        a2 = fmaf(e[j + 2], e[j + 2], a2);
        a3 = fmaf(e[j + 3], e[j + 3], a3);
    }
    ee[k] = (a0 + a1) + (a2 + a3);
}

// ===========================================================================
// Fully fused, all-LDS-fed register-blocked GEMMs. Block = 256 thr x 64 rows.
// Thread tile: tr=tid&7 -> rows tr*8..+7; tc=tid>>3 -> 4 cols (MLP) / 8
// codes (VQ). xT[128][68] holds x1^T then x2^T in place (acc in regs).
// LDS: xT 34.8K + unionA 34.3K (inT+wbuf during MLP / eL panel during VQ)
// + eeL 2K + vv 1.3K = 70.8 KB -> 2 blocks/CU.
// FP chains identical to rounds 1-9 (absmax 0.0): x1 s-asc, x2 t-asc,
// dot j-asc, vv = round-9 chain (4 sub-chains of 32, ((p0+p1)+p2)+p3),
// per-thread codes ascending strict <, cross-thread index tie-break, heads.
// ===========================================================================
__global__ __launch_bounds__(256, 2) void fused_kernel(
    const float* __restrict__ in,
    const float* __restrict__ W1, const float* __restrict__ b1,
    const float* __restrict__ Wh, const float* __restrict__ bh,
    const float* __restrict__ emb,
    const float* __restrict__ eT, const float* __restrict__ eew,
    const float* __restrict__ Wa, const float* __restrict__ ba,
    const float* __restrict__ Wv, const float* __restrict__ bv,
    float* __restrict__ out)
{
    __shared__ float xT[HDIM * XSTR];             // 8704 f = 34.8 KB
    __shared__ float uA[8576];                    // inT(4352) + wbuf(4224) | eL(8448)
    __shared__ float eeL[KCODES];                 // 2 KB
    __shared__ float vvp[4 * 64];                 // quarter partials
    __shared__ float vvf[64];                     // final vv per row
    float* inT  = uA;                             // [64][68]
    float* wbuf = uA + 4352;                      // [32][132]
    float* eL   = uA;                             // [32][264]

    const int tid = threadIdx.x;
    const int tr = tid & 7;                       // row group (8 rows)
    const int tc = tid >> 3;                      // col/code group
    const int brow = blockIdx.x * 64;

    // --- stage eeL + inT (transpose) + W1 chunk 0 ---
    eeL[tid] = eew[tid];
    eeL[256 + tid] = eew[256 + tid];
    {
        const float4* src = (const float4*)(in + (size_t)brow * SDIM);
#pragma unroll
        for (int u = 0; u < 4; ++u) {
            int idx = tid + 256 * u;              // 0..1023
            int r = idx >> 4, s4 = idx & 15;
            float4 v = src[idx];
            inT[(4 * s4 + 0) * XSTR + r] = v.x;
            inT[(4 * s4 + 1) * XSTR + r] = v.y;
            inT[(4 * s4 + 2) * XSTR + r] = v.z;
            inT[(4 * s4 + 3) * XSTR + r] = v.w;
        }
        const float4* w4 = (const float4*)W1;
#pragma unroll
        for (int u = 0; u < 4; ++u) {
            int idx = tid + 256 * u;
            int kk = idx >> 5, cq = idx & 31;
            *(float4*)(wbuf + kk * WSTR + 4 * cq) = w4[idx];
        }
    }
    __syncthreads();

    // --- layer1: a1[8][4], s ascending 0..63 (2 chunks of 32), exact ---
    float a1[8][4];
#pragma unroll
    for (int ri = 0; ri < 8; ++ri)
#pragma unroll
        for (int ci = 0; ci < 4; ++ci) a1[ri][ci] = b1[tc * 4 + ci];

    for (int kc = 0; kc < 2; ++kc) {
        if (kc > 0) {
            __syncthreads();                      // wbuf chunk0 consumed
            const float4* w4 = (const float4*)(W1 + 32 * HDIM);
#pragma unroll
            for (int u = 0; u < 4; ++u) {
                int idx = tid + 256 * u;
                int kk = idx >> 5, cq = idx & 31;
                *(float4*)(wbuf + kk * WSTR + 4 * cq) = w4[idx];
            }
            __syncthreads();
        }
#pragma unroll
        for (int k = 0; k < 32; ++k) {            // s = kc*32+k ascending
            float4 xa0 = *(const float4*)(inT + (kc * 32 + k) * XSTR + tr * 8);
            float4 xa1 = *(const float4*)(inT + (kc * 32 + k) * XSTR + tr * 8 + 4);
            float4 w = *(const float4*)(wbuf + k * WSTR + tc * 4);
#pragma unroll
            for (int ci = 0; ci < 4; ++ci) {
                float wc = ci == 0 ? w.x : ci == 1 ? w.y : ci == 2 ? w.z : w.w;
                a1[0][ci] = fmaf(xa0.x, wc, a1[0][ci]);
                a1[1][ci] = fmaf(xa0.y, wc, a1[1][ci]);
                a1[2][ci] = fmaf(xa0.z, wc, a1[2][ci]);
                a1[3][ci] = fmaf(xa0.w, wc, a1[3][ci]);
                a1[4][ci] = fmaf(xa1.x, wc, a1[4][ci]);
                a1[5][ci] = fmaf(xa1.y, wc, a1[5][ci]);
                a1[6][ci] = fmaf(xa1.z, wc, a1[6][ci]);
                a1[7][ci] = fmaf(xa1.w, wc, a1[7][ci]);
            }
        }
    }
    // write relu(x1) -> xT[col][row] (xT untouched so far; no pre-barrier)
#pragma unroll
    for (int ci = 0; ci < 4; ++ci) {
        float* dst = xT + (tc * 4 + ci) * XSTR + tr * 8;
        *(float4*)dst = make_float4(fmaxf(a1[0][ci], 0.f), fmaxf(a1[1][ci], 0.f),
                                    fmaxf(a1[2][ci], 0.f), fmaxf(a1[3][ci], 0.f));
        *(float4*)(dst + 4) = make_float4(fmaxf(a1[4][ci], 0.f), fmaxf(a1[5][ci], 0.f),
                                          fmaxf(a1[6][ci], 0.f), fmaxf(a1[7][ci], 0.f));
    }
    __syncthreads();                              // x1 visible; wbuf consumed

    // --- layer2: a2[8][4], t ascending 0..127 (4 chunks of 32), exact ---
    float a2[8][4];
#pragma unroll
    for (int ri = 0; ri < 8; ++ri)
#pragma unroll
        for (int ci = 0; ci < 4; ++ci) a2[ri][ci] = bh[tc * 4 + ci];

    for (int kc = 0; kc < 4; ++kc) {
        {
            const float4* w4 = (const float4*)(Wh + (size_t)kc * 32 * HDIM);
#pragma unroll
            for (int u = 0; u < 4; ++u) {
                int idx = tid + 256 * u;
                int kk = idx >> 5, cq = idx & 31;
                *(float4*)(wbuf + kk * WSTR + 4 * cq) = w4[idx];
            }
        }
        __syncthreads();
#pragma unroll
        for (int k = 0; k < 32; ++k) {            // t = kc*32+k ascending
            float4 xa0 = *(const float4*)(xT + (kc * 32 + k) * XSTR + tr * 8);
            float4 xa1 = *(const float4*)(xT + (kc * 32 + k) * XSTR + tr * 8 + 4);
            float4 w = *(const float4*)(wbuf + k * WSTR + tc * 4);
#pragma unroll
            for (int ci = 0; ci < 4; ++ci) {
                float wc = ci == 0 ? w.x : ci == 1 ? w.y : ci == 2 ? w.z : w.w;
                a2[0][ci] = fmaf(xa0.x, wc, a2[0][ci]);
                a2[1][ci] = fmaf(xa0.y, wc, a2[1][ci]);
                a2[2][ci] = fmaf(xa0.z, wc, a2[2][ci]);
                a2[3][ci] = fmaf(xa0.w, wc, a2[3][ci]);
                a2[4][ci] = fmaf(xa1.x, wc, a2[4][ci]);
                a2[5][ci] = fmaf(xa1.y, wc, a2[5][ci]);
                a2[6][ci] = fmaf(xa1.z, wc, a2[6][ci]);
                a2[7][ci] = fmaf(xa1.w, wc, a2[7][ci]);
            }
        }
        __syncthreads();                          // wbuf consumed / xT reads done
    }
    // overwrite xT with relu(x2) (barrier above guarantees all x1 reads done)
#pragma unroll
    for (int ci = 0; ci < 4; ++ci) {
        float* dst = xT + (tc * 4 + ci) * XSTR + tr * 8;
        *(float4*)dst = make_float4(fmaxf(a2[0][ci], 0.f), fmaxf(a2[1][ci], 0.f),
                                    fmaxf(a2[2][ci], 0.f), fmaxf(a2[3][ci], 0.f));
        *(float4*)(dst + 4) = make_float4(fmaxf(a2[4][ci], 0.f), fmaxf(a2[5][ci], 0.f),
                                          fmaxf(a2[6][ci], 0.f), fmaxf(a2[7][ci], 0.f));
    }
    __syncthreads();                              // x2 visible

    // --- vv: round-9 exact chain. quarter q over j=q*32..+31 (fmaf asc),
    //     combine ((p0+p1)+p2)+p3 ---
    {
        const int q = tid >> 6, r = tid & 63;
        float p = 0.f;
#pragma unroll 8
        for (int j = q * 32; j < q * 32 + 32; ++j) {
            float v = xT[j * XSTR + r];
            p = fmaf(v, v, p);
        }
        vvp[q * 64 + r] = p;
    }
    __syncthreads();
    if (tid < 64)
        vvf[tid] = ((vvp[tid] + vvp[64 + tid]) + vvp[128 + tid]) + vvp[192 + tid];
    __syncthreads();

    float vvr[8];
#pragma unroll
    for (int ri = 0; ri < 8; ++ri) vvr[ri] = vvf[tr * 8 + ri];

    // --- VQ scoring: 2 panels of 256 codes; thread = 8 rows x 8 codes ---
    float best[8];
    int bix[8];
#pragma unroll
    for (int ri = 0; ri < 8; ++ri) { best[ri] = FLT_MAX; bix[ri] = 0; }

    for (int cb = 0; cb < 2; ++cb) {
        float d[8][8];
#pragma unroll
        for (int ri = 0; ri < 8; ++ri)
#pragma unroll
            for (int ci = 0; ci < 8; ++ci) d[ri][ci] = 0.f;

        for (int kc = 0; kc < 4; ++kc) {
            __syncthreads();                      // eL consumed (or uA dead 1st time)
            {
                const float4* e4 = (const float4*)(eT + (size_t)kc * 32 * KCODES + cb * 256);
#pragma unroll
                for (int u = 0; u < 8; ++u) {
                    int idx = tid + 256 * u;      // 0..2047
                    int kk = idx >> 6, cq = idx & 63;
                    *(float4*)(eL + kk * ESTR + 4 * cq) = e4[(size_t)kk * (KCODES / 4) + cq];
                }
            }
            __syncthreads();
#pragma unroll
            for (int k = 0; k < 32; ++k) {        // j = kc*32+k ascending
                float4 xa0 = *(const float4*)(xT + (kc * 32 + k) * XSTR + tr * 8);
                float4 xa1 = *(const float4*)(xT + (kc * 32 + k) * XSTR + tr * 8 + 4);
                float4 e0 = *(const float4*)(eL + k * ESTR + tc * 8);
                float4 e1 = *(const float4*)(eL + k * ESTR + tc * 8 + 4);
#pragma unroll
                for (int ci = 0; ci < 8; ++ci) {
                    float ec = ci == 0 ? e0.x : ci == 1 ? e0.y : ci == 2 ? e0.z :
                               ci == 3 ? e0.w : ci == 4 ? e1.x : ci == 5 ? e1.y :
                               ci == 6 ? e1.z : e1.w;
                    d[0][ci] = fmaf(xa0.x, ec, d[0][ci]);
                    d[1][ci] = fmaf(xa0.y, ec, d[1][ci]);
                    d[2][ci] = fmaf(xa0.z, ec, d[2][ci]);
                    d[3][ci] = fmaf(xa0.w, ec, d[3][ci]);
                    d[4][ci] = fmaf(xa1.x, ec, d[4][ci]);
                    d[5][ci] = fmaf(xa1.y, ec, d[5][ci]);
                    d[6][ci] = fmaf(xa1.z, ec, d[6][ci]);
                    d[7][ci] = fmaf(xa1.w, ec, d[7][ci]);
                }
            }
        }
        // epilogue: codes ascending (cb asc outer, ci asc inner), strict <
        const int cbase = cb * 256 + tc * 8;
#pragma unroll
        for (int ci = 0; ci < 8; ++ci) {
            float ec = eeL[cbase + ci];
#pragma unroll
            for (int ri = 0; ri < 8; ++ri) {
                float dd = (vvr[ri] - 2.f * d[ri][ci]) + ec;
                if (dd < best[ri]) { best[ri] = dd; bix[ri] = cbase + ci; }
            }
        }
    }

    // --- cross-thread argmin: 32 candidates/row, index tie-break = first-min ---
    __syncthreads();                              // xT reads done; overlay red
    float* redB = xT;                             // [64][33]
    int*   redI = (int*)(xT + 64 * 33);
#pragma unroll
    for (int ri = 0; ri < 8; ++ri) {
        redB[(tr * 8 + ri) * 33 + tc] = best[ri];
        redI[(tr * 8 + ri) * 33 + tc] = bix[ri];
    }
    __syncthreads();

    if (tid < 64) {
        float bb = redB[tid * 33];
        int bx = redI[tid * 33];
#pragma unroll
        for (int q = 1; q < 32; ++q) {
            float b = redB[tid * 33 + q];
            int i = redI[tid * 33 + q];
            if (b < bb || (b == bb && i < bx)) { bb = b; bx = i; }
        }

        // --- heads: quantize = emb[bx]; exact FP order of rounds 1-9 ---
        const int row = brow + tid;
        float lg[ADIM];
#pragma unroll
        for (int a = 0; a < ADIM; ++a) lg[a] = ba[a];
        float val = bv[0];

        const float4* q4 = (const float4*)(emb + (size_t)bx * HDIM);
#pragma unroll
        for (int j4 = 0; j4 < HDIM / 4; ++j4) {
            float4 q = q4[j4];
            const int j = 4 * j4;
#pragma unroll
            for (int a = 0; a < ADIM; ++a) {
                float t = lg[a];
                t = fmaf(q.x, Wa[(j + 0) * ADIM + a], t);
                t = fmaf(q.y, Wa[(j + 1) * ADIM + a], t);
                t = fmaf(q.z, Wa[(j + 2) * ADIM + a], t);
                t = fmaf(q.w, Wa[(j + 3) * ADIM + a], t);
                lg[a] = t;
            }
            val = fmaf(q.x, Wv[j + 0], val);
            val = fmaf(q.y, Wv[j + 1], val);
            val = fmaf(q.z, Wv[j + 2], val);
            val = fmaf(q.w, Wv[j + 3], val);
        }

        float m = lg[0];
#pragma unroll
        for (int a = 1; a < ADIM; ++a) m = fmaxf(m, lg[a]);
        float p[ADIM];
        float s = 0.f;
#pragma unroll
        for (int a = 0; a < ADIM; ++a) { p[a] = __expf(lg[a] - m); s += p[a]; }
        const float inv = 1.f / s;

        float4* outp = (float4*)(out + (size_t)row * ADIM);
        outp[0] = make_float4(p[0] * inv, p[1] * inv, p[2] * inv, p[3] * inv);
        outp[1] = make_float4(p[4] * inv, p[5] * inv, p[6] * inv, p[7] * inv);
        out[(size_t)NROWS * ADIM + row] = val;
    }
}

// ===========================================================================
// Fallback (ws too small; never expected): round-4 global-feed path.
// ===========================================================================
#define R16(M) M(0) M(1) M(2) M(3) M(4) M(5) M(6) M(7) \
               M(8) M(9) M(10) M(11) M(12) M(13) M(14) M(15)
#define R32(M) R16(M) M(16) M(17) M(18) M(19) M(20) M(21) M(22) M(23) \
               M(24) M(25) M(26) M(27) M(28) M(29) M(30) M(31)
#define PIN4(v) asm volatile("" : "+v"(v.x), "+v"(v.y), "+v"(v.z), "+v"(v.w));

__global__ __launch_bounds__(256, 2) void fused_global_kernel(
    const float* __restrict__ in,
    const float* __restrict__ W1, const float* __restrict__ b1,
    const float* __restrict__ Wh, const float* __restrict__ bh,
    const float* __restrict__ emb,
    const float* __restrict__ Wa, const float* __restrict__ ba,
    const float* __restrict__ Wv, const float* __restrict__ bv,
    float* __restrict__ out)
{
    __shared__ float ee_s[KCODES];
    const int tid = threadIdx.x;
    const int row = blockIdx.x * 256 + tid;

#pragma unroll
    for (int kk = 0; kk < 2; ++kk) {
        int k = tid + 256 * kk;
        const float* e = emb + k * HDIM;
        float a0 = 0.f, a1 = 0.f, a2 = 0.f, a3 = 0.f;
#pragma unroll
        for (int j = 0; j < HDIM; j += 4) {
            a0 = fmaf(e[j + 0], e[j + 0], a0);
            a1 = fmaf(e[j + 1], e[j + 1], a1);
            a2 = fmaf(e[j + 2], e[j + 2], a2);
            a3 = fmaf(e[j + 3], e[j + 3], a3);
        }
        ee_s[k] = (a0 + a1) + (a2 + a3);
    }
    __syncthreads();

    const float4* inr4 = (const float4*)(in + (size_t)row * SDIM);
#define DECLI(n) float4 i##n = inr4[n]; PIN4(i##n)
    R16(DECLI)
#define DECLX(m) float4 x##m = make_float4(bh[4*(m)+0], bh[4*(m)+1], bh[4*(m)+2], bh[4*(m)+3]);
    R32(DECLX)

#define L1N(n) xt = fmaf(i##n.x, wc[(4*(n)+0)*HDIM], xt); xt = fmaf(i##n.y, wc[(4*(n)+1)*HDIM], xt); \
               xt = fmaf(i##n.z, wc[(4*(n)+2)*HDIM], xt); xt = fmaf(i##n.w, wc[(4*(n)+3)*HDIM], xt);
#define L2(m)  x##m.x = fmaf(xt, whr[4*(m)+0], x##m.x); x##m.y = fmaf(xt, whr[4*(m)+1], x##m.y); \
               x##m.z = fmaf(xt, whr[4*(m)+2], x##m.z); x##m.w = fmaf(xt, whr[4*(m)+3], x##m.w);
    for (int t = 0; t < HDIM; ++t) {
        float xt = b1[t];
        const float* wc = W1 + t;
        R16(L1N)
        xt = fmaxf(xt, 0.f);
        const float* whr = Wh + t * HDIM;
        R32(L2)
    }
#define RELUX(m) x##m.x = fmaxf(x##m.x, 0.f); x##m.y = fmaxf(x##m.y, 0.f); \
                 x##m.z = fmaxf(x##m.z, 0.f); x##m.w = fmaxf(x##m.w, 0.f); PIN4(x##m)
    R32(RELUX)

    float v0 = 0.f, v1 = 0.f, v2 = 0.f, v3 = 0.f;
#define VV(m) v0 = fmaf(x##m.x, x##m.x, v0); v1 = fmaf(x##m.y, x##m.y, v1); \
              v2 = fmaf(x##m.z, x##m.z, v2); v3 = fmaf(x##m.w, x##m.w, v3);
    R32(VV)
    const float vv = (v0 + v1) + (v2 + v3);

    float best = FLT_MAX;
    int bi = 0;
#define SC(m) \
    d0 = fmaf(x##m.x, eb[0*HDIM+4*(m)+0], d0); d0 = fmaf(x##m.y, eb[0*HDIM+4*(m)+1], d0); \
    d0 = fmaf(x##m.z, eb[0*HDIM+4*(m)+2], d0); d0 = fmaf(x##m.w, eb[0*HDIM+4*(m)+3], d0); \
    d1 = fmaf(x##m.x, eb[1*HDIM+4*(m)+0], d1); d1 = fmaf(x##m.y, eb[1*HDIM+4*(m)+1], d1); \
    d1 = fmaf(x##m.z, eb[1*HDIM+4*(m)+2], d1); d1 = fmaf(x##m.w, eb[1*HDIM+4*(m)+3], d1); \
    d2 = fmaf(x##m.x, eb[2*HDIM+4*(m)+0], d2); d2 = fmaf(x##m.y, eb[2*HDIM+4*(m)+1], d2); \
    d2 = fmaf(x##m.z, eb[2*HDIM+4*(m)+2], d2); d2 = fmaf(x##m.w, eb[2*HDIM+4*(m)+3], d2); \
    d3 = fmaf(x##m.x, eb[3*HDIM+4*(m)+0], d3); d3 = fmaf(x##m.y, eb[3*HDIM+4*(m)+1], d3); \
    d3 = fmaf(x##m.z, eb[3*HDIM+4*(m)+2], d3); d3 = fmaf(x##m.w, eb[3*HDIM+4*(m)+3], d3); \
    d4 = fmaf(x##m.x, eb[4*HDIM+4*(m)+0], d4); d4 = fmaf(x##m.y, eb[4*HDIM+4*(m)+1], d4); \
    d4 = fmaf(x##m.z, eb[4*HDIM+4*(m)+2], d4); d4 = fmaf(x##m.w, eb[4*HDIM+4*(m)+3], d4); \
    d5 = fmaf(x##m.x, eb[5*HDIM+4*(m)+0], d5); d5 = fmaf(x##m.y, eb[5*HDIM+4*(m)+1], d5); \
    d5 = fmaf(x##m.z, eb[5*HDIM+4*(m)+2], d5); d5 = fmaf(x##m.w, eb[5*HDIM+4*(m)+3], d5); \
    d6 = fmaf(x##m.x, eb[6*HDIM+4*(m)+0], d6); d6 = fmaf(x##m.y, eb[6*HDIM+4*(m)+1], d6); \
    d6 = fmaf(x##m.z, eb[6*HDIM+4*(m)+2], d6); d6 = fmaf(x##m.w, eb[6*HDIM+4*(m)+3], d6); \
    d7 = fmaf(x##m.x, eb[7*HDIM+4*(m)+0], d7); d7 = fmaf(x##m.y, eb[7*HDIM+4*(m)+1], d7); \
    d7 = fmaf(x##m.z, eb[7*HDIM+4*(m)+2], d7); d7 = fmaf(x##m.w, eb[7*HDIM+4*(m)+3], d7);
    for (int k0 = 0; k0 < KCODES; k0 += 8) {
        const float* eb = emb + (size_t)k0 * HDIM;
        float d0 = 0.f, d1 = 0.f, d2 = 0.f, d3 = 0.f;
        float d4 = 0.f, d5 = 0.f, d6 = 0.f, d7 = 0.f;
        R32(SC)
        float dd;
        dd = (vv - 2.f * d0) + ee_s[k0 + 0]; if (dd < best) { best = dd; bi = k0 + 0; }
        dd = (vv - 2.f * d1) + ee_s[k0 + 1]; if (dd < best) { best = dd; bi = k0 + 1; }
        dd = (vv - 2.f * d2) + ee_s[k0 + 2]; if (dd < best) { best = dd; bi = k0 + 2; }
        dd = (vv - 2.f * d3) + ee_s[k0 + 3]; if (dd < best) { best = dd; bi = k0 + 3; }
        dd = (vv - 2.f * d4) + ee_s[k0 + 4]; if (dd < best) { best = dd; bi = k0 + 4; }
        dd = (vv - 2.f * d5) + ee_s[k0 + 5]; if (dd < best) { best = dd; bi = k0 + 5; }
        dd = (vv - 2.f * d6) + ee_s[k0 + 6]; if (dd < best) { best = dd; bi = k0 + 6; }
        dd = (vv - 2.f * d7) + ee_s[k0 + 7]; if (dd < best) { best = dd; bi = k0 + 7; }
    }

    float lg[ADIM];
#pragma unroll
    for (int a = 0; a < ADIM; ++a) lg[a] = ba[a];
    float val = bv[0];
    const float4* q4 = (const float4*)(emb + (size_t)bi * HDIM);
#pragma unroll
    for (int j4 = 0; j4 < HDIM / 4; ++j4) {
        float4 q = q4[j4];
        const int j = 4 * j4;
#pragma unroll
        for (int a = 0; a < ADIM; ++a) {
            float t = lg[a];
            t = fmaf(q.x, Wa[(j + 0) * ADIM + a], t);
            t = fmaf(q.y, Wa[(j + 1) * ADIM + a], t);
            t = fmaf(q.z, Wa[(j + 2) * ADIM + a], t);
            t = fmaf(q.w, Wa[(j + 3) * ADIM + a], t);
            lg[a] = t;
        }
        val = fmaf(q.x, Wv[j + 0], val);
        val = fmaf(q.y, Wv[j + 1], val);
        val = fmaf(q.z, Wv[j + 2], val);
        val = fmaf(q.w, Wv[j + 3], val);
    }
    float m = lg[0];
#pragma unroll
    for (int a = 1; a < ADIM; ++a) m = fmaxf(m, lg[a]);
    float p[ADIM];
    float s = 0.f;
#pragma unroll
    for (int a = 0; a < ADIM; ++a) { p[a] = __expf(lg[a] - m); s += p[a]; }
    const float inv = 1.f / s;
    float4* outp = (float4*)(out + (size_t)row * ADIM);
    outp[0] = make_float4(p[0] * inv, p[1] * inv, p[2] * inv, p[3] * inv);
    outp[1] = make_float4(p[4] * inv, p[5] * inv, p[6] * inv, p[7] * inv);
    out[(size_t)NROWS * ADIM + row] = val;
}

// ===========================================================================
extern "C" void kernel_launch(void* const* d_in, const int* in_sizes, int n_in,
                              void* d_out, int out_size, void* d_ws, size_t ws_size,
                              hipStream_t stream) {
    const float* in  = (const float*)d_in[0];
    const float* W1  = (const float*)d_in[1];
    const float* b1  = (const float*)d_in[2];
    const float* Wh  = (const float*)d_in[3];
    const float* bh  = (const float*)d_in[4];
    const float* emb = (const float*)d_in[5];
    const float* Wa  = (const float*)d_in[6];
    const float* ba  = (const float*)d_in[7];
    const float* Wv  = (const float*)d_in[8];
    const float* bv  = (const float*)d_in[9];
    float* out = (float*)d_out;

    const size_t eT_f = (size_t)KCODES * HDIM;            // 256 KB
    const size_t need = (eT_f + KCODES) * sizeof(float);

    if (ws_size >= need) {
        float* eTp = (float*)d_ws;
        float* eew = eTp + eT_f;
        prep_e_kernel<<<64, 256, 0, stream>>>(emb, eTp);
        ee_kernel<<<2, 256, 0, stream>>>(emb, eew);
        fused_kernel<<<NROWS / 64, 256, 0, stream>>>(in, W1, b1, Wh, bh, emb,
                                                     eTp, eew, Wa, ba, Wv, bv, out);
    } else {
        fused_global_kernel<<<NROWS / 256, 256, 0, stream>>>(in, W1, b1, Wh, bh, emb,
                                                             Wa, ba, Wv, bv, out);
    }
}

// Round 11
// 417.977 us; speedup vs baseline: 1.0008x; 1.0008x over previous
//
#include <hip/hip_runtime.h>
#include <math.h>
#include <float.h>

#define NROWS 131072
#define SDIM 64
#define HDIM 128
#define KCODES 512
#define ADIM 8

#define vvA_q(q) ((q) == 0 ? vvA.x : (q) == 1 ? vvA.y : (q) == 2 ? vvA.z : vvA.w)
#define vvB_q(q) ((q) == 0 ? vvB.x : (q) == 1 ? vvB.y : (q) == 2 ? vvB.z : vvB.w)

// ===========================================================================
// prep: eT[j][c] = emb[c][j]  (256 KB), j-major (identical to round 9).
// ===========================================================================
__global__ void prep_e_kernel(const float* __restrict__ emb, float* __restrict__ eT) {
    int g = blockIdx.x * 256 + threadIdx.x;        // 0..16383
    int c = g >> 5, j4 = g & 31;
    float4 v = ((const float4*)emb)[(size_t)c * 32 + j4];
    eT[(size_t)(4 * j4 + 0) * KCODES + c] = v.x;
    eT[(size_t)(4 * j4 + 1) * KCODES + c] = v.y;
    eT[(size_t)(4 * j4 + 2) * KCODES + c] = v.z;
    eT[(size_t)(4 * j4 + 3) * KCODES + c] = v.w;
}

// ee[k] = sum_j emb[k][j]^2 — exact FP chain from rounds 1-10 (absmax 0.0)
__global__ void ee_kernel(const float* __restrict__ emb, float* __restrict__ ee) {
    int k = blockIdx.x * blockDim.x + threadIdx.x;
    if (k >= KCODES) return;
    const float* e = emb + k * HDIM;
    float a0 = 0.f, a1 = 0.f, a2 = 0.f, a3 = 0.f;
#pragma unroll
    for (int j = 0; j < HDIM; j += 4) {
        a0 = fmaf(e[j + 0], e[j + 0], a0);
        a1 = fmaf(e[j + 1], e[j + 1], a1);
        a2 = fmaf(e[j + 2], e[j + 2], a2);
        a3 = fmaf(e[j + 3], e[j + 3], a3);
    }
    ee[k] = (a0 + a1) + (a2 + a3);
}

// ===========================================================================
// MLP, LDS-fed register-blocked (replaces round-9's scalar-fed version).
// Block = 256 thr x 64 rows; tr=tid&7 -> rows tr*8..+7; tc=tid>>3 -> cols
// tc*4..+3. Per k-step: 3 conflict-free ds_read_b128 -> 32 FMA. W1/Wh in
// 32-k LDS chunks; x1^T resident in LDS. Chains exact: x1 s-asc 0..63,
// x2 t-asc 0..127, single acc per (row,col). Writes x2^T + vvs (vv chain
// argmin-invariant; validated in round 10 with absmax 0.0).
// LDS: inT 17.4K + x1T 34.8K + wbuf 16.9K = 69.1 KB -> 2 blocks/CU.
// __launch_bounds__(256,4): VGPR cap 128 (32 accs; round-9 vq proved 64 ok).
// ===========================================================================
__global__ __launch_bounds__(256, 4) void mlp_kernel(
    const float* __restrict__ in,
    const float* __restrict__ W1, const float* __restrict__ b1,
    const float* __restrict__ Wh, const float* __restrict__ bh,
    float* __restrict__ x2t, float* __restrict__ vvs, int rstride)
{
    __shared__ float inT[64 * 68];                // 17.4 KB (vvp overlays later)
    __shared__ float x1T[HDIM * 68];              // 34.8 KB
    __shared__ float wbuf[32 * 132];              // 16.9 KB
    const int tid = threadIdx.x;
    const int tr = tid & 7;
    const int tc = tid >> 3;
    const int brow = blockIdx.x * 64;

    // stage inT[s][r] = in[brow+r][s]
    {
        const float4* src = (const float4*)(in + (size_t)brow * SDIM);
#pragma unroll
        for (int u = 0; u < 4; ++u) {
            int idx = tid + 256 * u;              // 0..1023
            int r = idx >> 4, s4 = idx & 15;
            float4 v = src[idx];
            inT[(4 * s4 + 0) * 68 + r] = v.x;
            inT[(4 * s4 + 1) * 68 + r] = v.y;
            inT[(4 * s4 + 2) * 68 + r] = v.z;
            inT[(4 * s4 + 3) * 68 + r] = v.w;
        }
    }

    // --- layer1: a1[8][4], s ascending (2 chunks of 32), exact chain ---
    float a1[8][4];
#pragma unroll
    for (int ri = 0; ri < 8; ++ri)
#pragma unroll
        for (int ci = 0; ci < 4; ++ci) a1[ri][ci] = b1[tc * 4 + ci];

    for (int kc = 0; kc < 2; ++kc) {
        __syncthreads();                          // prev wbuf reads / inT stage done
        {
            const float4* w4 = (const float4*)(W1 + (size_t)kc * 32 * HDIM);
#pragma unroll
            for (int u = 0; u < 4; ++u) {
                int idx = tid + 256 * u;          // 0..1023
                int kk = idx >> 5, cq = idx & 31;
                *(float4*)(wbuf + kk * 132 + 4 * cq) = w4[idx];
            }
        }
        __syncthreads();
#pragma unroll
        for (int k = 0; k < 32; ++k) {            // s = kc*32+k ascending
            float4 xa0 = *(const float4*)(inT + (kc * 32 + k) * 68 + tr * 8);
            float4 xa1 = *(const float4*)(inT + (kc * 32 + k) * 68 + tr * 8 + 4);
            float4 w = *(const float4*)(wbuf + k * 132 + tc * 4);
#pragma unroll
            for (int ci = 0; ci < 4; ++ci) {
                float wc = ci == 0 ? w.x : ci == 1 ? w.y : ci == 2 ? w.z : w.w;
                a1[0][ci] = fmaf(xa0.x, wc, a1[0][ci]);
                a1[1][ci] = fmaf(xa0.y, wc, a1[1][ci]);
                a1[2][ci] = fmaf(xa0.z, wc, a1[2][ci]);
                a1[3][ci] = fmaf(xa0.w, wc, a1[3][ci]);
                a1[4][ci] = fmaf(xa1.x, wc, a1[4][ci]);
                a1[5][ci] = fmaf(xa1.y, wc, a1[5][ci]);
                a1[6][ci] = fmaf(xa1.z, wc, a1[6][ci]);
                a1[7][ci] = fmaf(xa1.w, wc, a1[7][ci]);
            }
        }
    }
    // relu(x1) -> x1T[c][r]
#pragma unroll
    for (int ci = 0; ci < 4; ++ci) {
        float* dst = x1T + (tc * 4 + ci) * 68 + tr * 8;
        *(float4*)dst = make_float4(fmaxf(a1[0][ci], 0.f), fmaxf(a1[1][ci], 0.f),
                                    fmaxf(a1[2][ci], 0.f), fmaxf(a1[3][ci], 0.f));
        *(float4*)(dst + 4) = make_float4(fmaxf(a1[4][ci], 0.f), fmaxf(a1[5][ci], 0.f),
                                          fmaxf(a1[6][ci], 0.f), fmaxf(a1[7][ci], 0.f));
    }

    // --- layer2: a2[8][4], t ascending (4 chunks of 32), exact chain ---
    float a2[8][4];
#pragma unroll
    for (int ri = 0; ri < 8; ++ri)
#pragma unroll
        for (int ci = 0; ci < 4; ++ci) a2[ri][ci] = bh[tc * 4 + ci];

    for (int kc = 0; kc < 4; ++kc) {
        __syncthreads();                          // x1 visible / prev wbuf reads done
        {
            const float4* w4 = (const float4*)(Wh + (size_t)kc * 32 * HDIM);
#pragma unroll
            for (int u = 0; u < 4; ++u) {
                int idx = tid + 256 * u;
                int kk = idx >> 5, cq = idx & 31;
                *(float4*)(wbuf + kk * 132 + 4 * cq) = w4[idx];
            }
        }
        __syncthreads();
#pragma unroll
        for (int k = 0; k < 32; ++k) {            // t = kc*32+k ascending
            float4 xa0 = *(const float4*)(x1T + (kc * 32 + k) * 68 + tr * 8);
            float4 xa1 = *(const float4*)(x1T + (kc * 32 + k) * 68 + tr * 8 + 4);
            float4 w = *(const float4*)(wbuf + k * 132 + tc * 4);
#pragma unroll
            for (int ci = 0; ci < 4; ++ci) {
                float wc = ci == 0 ? w.x : ci == 1 ? w.y : ci == 2 ? w.z : w.w;
                a2[0][ci] = fmaf(xa0.x, wc, a2[0][ci]);
                a2[1][ci] = fmaf(xa0.y, wc, a2[1][ci]);
                a2[2][ci] = fmaf(xa0.z, wc, a2[2][ci]);
                a2[3][ci] = fmaf(xa0.w, wc, a2[3][ci]);
                a2[4][ci] = fmaf(xa1.x, wc, a2[4][ci]);
                a2[5][ci] = fmaf(xa1.y, wc, a2[5][ci]);
                a2[6][ci] = fmaf(xa1.z, wc, a2[6][ci]);
                a2[7][ci] = fmaf(xa1.w, wc, a2[7][ci]);
            }
        }
    }

    // relu(x2) -> global x2^T, plus per-thread vv partials
    float pv[8];
#pragma unroll
    for (int ri = 0; ri < 8; ++ri) pv[ri] = 0.f;
#pragma unroll
    for (int ci = 0; ci < 4; ++ci) {
        float r0 = fmaxf(a2[0][ci], 0.f), r1 = fmaxf(a2[1][ci], 0.f);
        float r2 = fmaxf(a2[2][ci], 0.f), r3 = fmaxf(a2[3][ci], 0.f);
        float r4 = fmaxf(a2[4][ci], 0.f), r5 = fmaxf(a2[5][ci], 0.f);
        float r6 = fmaxf(a2[6][ci], 0.f), r7 = fmaxf(a2[7][ci], 0.f);
        float* dst = x2t + (size_t)(tc * 4 + ci) * rstride + brow + tr * 8;
        *(float4*)dst = make_float4(r0, r1, r2, r3);
        *(float4*)(dst + 4) = make_float4(r4, r5, r6, r7);
        pv[0] = fmaf(r0, r0, pv[0]); pv[1] = fmaf(r1, r1, pv[1]);
        pv[2] = fmaf(r2, r2, pv[2]); pv[3] = fmaf(r3, r3, pv[3]);
        pv[4] = fmaf(r4, r4, pv[4]); pv[5] = fmaf(r5, r5, pv[5]);
        pv[6] = fmaf(r6, r6, pv[6]); pv[7] = fmaf(r7, r7, pv[7]);
    }
    __syncthreads();                              // inT long dead; reuse as vvp
    float* vvp = inT;                             // [64][33]
#pragma unroll
    for (int ri = 0; ri < 8; ++ri)
        vvp[(tr * 8 + ri) * 33 + tc] = pv[ri];
    __syncthreads();
    if (tid < 64) {
        float vv = vvp[tid * 33];
#pragma unroll
        for (int q = 1; q < 32; ++q) vv += vvp[tid * 33 + q];   // tc ascending
        vvs[brow + tid] = vv;
    }
}

// ===========================================================================
// VQ: byte-identical to round 9 (247 us, VALUBusy 72%, no spill).
// ===========================================================================
__global__ __launch_bounds__(256, 4) void vq_kernel(
    const float* __restrict__ x2t, const float* __restrict__ eT,
    const float* __restrict__ eew, const float* __restrict__ vvs,
    const float* __restrict__ emb,
    const float* __restrict__ Wa, const float* __restrict__ ba,
    const float* __restrict__ Wv, const float* __restrict__ bv,
    float* __restrict__ out, int rstride)
{
    __shared__ float smem[4224 * 2 + 512];        // 35 KB
    float* xL  = smem;                            // [32][132]
    float* eL  = smem + 4224;                     // [32][132]
    float* eeL = smem + 8448;                     // [512]
    const int tid = threadIdx.x;
    const int tr = tid & 15;
    const int tc = tid >> 4;
    const int brow = blockIdx.x * 128;

    eeL[tid] = eew[tid];
    eeL[tid + 256] = eew[tid + 256];

    float4 vvA = *(const float4*)(vvs + brow + tr * 4);
    float4 vvB = *(const float4*)(vvs + brow + 64 + tr * 4);

    float bestA[4], bestB[4];
    int biA[4], biB[4];
#pragma unroll
    for (int q = 0; q < 4; ++q) {
        bestA[q] = FLT_MAX; bestB[q] = FLT_MAX; biA[q] = 0; biB[q] = 0;
    }

#define FMA8(ri, xv) \
    acc[ri][0] = fmaf(xv, e0.x, acc[ri][0]); acc[ri][1] = fmaf(xv, e0.y, acc[ri][1]); \
    acc[ri][2] = fmaf(xv, e0.z, acc[ri][2]); acc[ri][3] = fmaf(xv, e0.w, acc[ri][3]); \
    acc[ri][4] = fmaf(xv, e1.x, acc[ri][4]); acc[ri][5] = fmaf(xv, e1.y, acc[ri][5]); \
    acc[ri][6] = fmaf(xv, e1.z, acc[ri][6]); acc[ri][7] = fmaf(xv, e1.w, acc[ri][7]);

    for (int cb = 0; cb < 4; ++cb) {
        float acc[8][8];
#pragma unroll
        for (int ri = 0; ri < 8; ++ri)
#pragma unroll
            for (int ci = 0; ci < 8; ++ci) acc[ri][ci] = 0.f;

        for (int kc = 0; kc < 4; ++kc) {
            __syncthreads();                      // prev chunk consumed
#pragma unroll
            for (int u = 0; u < 4; ++u) {
                int idx = tid + 256 * u;          // 0..1023
                int kk = idx >> 5, rq = idx & 31;
                float4 xv = *(const float4*)(x2t + (size_t)(kc * 32 + kk) * rstride + brow + 4 * rq);
                *(float4*)(xL + kk * 132 + 4 * rq) = xv;
                float4 ev = *(const float4*)(eT + (size_t)(kc * 32 + kk) * KCODES + cb * 128 + 4 * rq);
                *(float4*)(eL + kk * 132 + 4 * rq) = ev;
            }
            __syncthreads();
#pragma unroll 2
            for (int k = 0; k < 32; ++k) {        // k ascending: exact dot chain
                float4 xa = *(const float4*)(xL + k * 132 + tr * 4);
                float4 xb = *(const float4*)(xL + k * 132 + 64 + tr * 4);
                float4 e0 = *(const float4*)(eL + k * 132 + tc * 8);
                float4 e1 = *(const float4*)(eL + k * 132 + tc * 8 + 4);
                FMA8(0, xa.x) FMA8(1, xa.y) FMA8(2, xa.z) FMA8(3, xa.w)
                FMA8(4, xb.x) FMA8(5, xb.y) FMA8(6, xb.z) FMA8(7, xb.w)
            }
        }
        const int cbase = cb * 128 + tc * 8;
#pragma unroll
        for (int ci = 0; ci < 8; ++ci) {
            float ec = eeL[cbase + ci];
#pragma unroll
            for (int q = 0; q < 4; ++q) {
                float dd = (vvA_q(q) - 2.f * acc[q][ci]) + ec;
                if (dd < bestA[q]) { bestA[q] = dd; biA[q] = cbase + ci; }
                float dd2 = (vvB_q(q) - 2.f * acc[4 + q][ci]) + ec;
                if (dd2 < bestB[q]) { bestB[q] = dd2; biB[q] = cbase + ci; }
            }
        }
    }
#undef FMA8

    __syncthreads();                              // compute done; reuse smem
    float* redB = smem;                           // [128][17]
    int*   redI = (int*)(smem + 2304);            // [128][17]
#pragma unroll
    for (int q = 0; q < 4; ++q) {
        redB[(tr * 4 + q) * 17 + tc] = bestA[q];
        redI[(tr * 4 + q) * 17 + tc] = biA[q];
        redB[(64 + tr * 4 + q) * 17 + tc] = bestB[q];
        redI[(64 + tr * 4 + q) * 17 + tc] = biB[q];
    }
    __syncthreads();

    if (tid < 128) {
        float bb = redB[tid * 17];
        int bix = redI[tid * 17];
#pragma unroll
        for (int q = 1; q < 16; ++q) {
            float b = redB[tid * 17 + q];
            int i = redI[tid * 17 + q];
            if (b < bb || (b == bb && i < bix)) { bb = b; bix = i; }
        }

        const int row = brow + tid;
        float lg[ADIM];
#pragma unroll
        for (int a = 0; a < ADIM; ++a) lg[a] = ba[a];
        float val = bv[0];

        const float4* q4 = (const float4*)(emb + (size_t)bix * HDIM);
#pragma unroll
        for (int j4 = 0; j4 < HDIM / 4; ++j4) {
            float4 q = q4[j4];
            const int j = 4 * j4;
#pragma unroll
            for (int a = 0; a < ADIM; ++a) {
                float t = lg[a];
                t = fmaf(q.x, Wa[(j + 0) * ADIM + a], t);
                t = fmaf(q.y, Wa[(j + 1) * ADIM + a], t);
                t = fmaf(q.z, Wa[(j + 2) * ADIM + a], t);
                t = fmaf(q.w, Wa[(j + 3) * ADIM + a], t);
                lg[a] = t;
            }
            val = fmaf(q.x, Wv[j + 0], val);
            val = fmaf(q.y, Wv[j + 1], val);
            val = fmaf(q.z, Wv[j + 2], val);
            val = fmaf(q.w, Wv[j + 3], val);
        }

        float m = lg[0];
#pragma unroll
        for (int a = 1; a < ADIM; ++a) m = fmaxf(m, lg[a]);
        float p[ADIM];
        float s = 0.f;
#pragma unroll
        for (int a = 0; a < ADIM; ++a) { p[a] = __expf(lg[a] - m); s += p[a]; }
        const float inv = 1.f / s;

        float4* outp = (float4*)(out + (size_t)row * ADIM);
        outp[0] = make_float4(p[0] * inv, p[1] * inv, p[2] * inv, p[3] * inv);
        outp[1] = make_float4(p[4] * inv, p[5] * inv, p[6] * inv, p[7] * inv);
        out[(size_t)NROWS * ADIM + row] = val;
    }
}

// ===========================================================================
// Fallback (ws too small; never expected): round-4 global-feed path.
// ===========================================================================
#define R16(M) M(0) M(1) M(2) M(3) M(4) M(5) M(6) M(7) \
               M(8) M(9) M(10) M(11) M(12) M(13) M(14) M(15)
#define R32(M) R16(M) M(16) M(17) M(18) M(19) M(20) M(21) M(22) M(23) \
               M(24) M(25) M(26) M(27) M(28) M(29) M(30) M(31)
#define PIN4(v) asm volatile("" : "+v"(v.x), "+v"(v.y), "+v"(v.z), "+v"(v.w));

__global__ __launch_bounds__(256, 2) void fused_global_kernel(
    const float* __restrict__ in,
    const float* __restrict__ W1, const float* __restrict__ b1,
    const float* __restrict__ Wh, const float* __restrict__ bh,
    const float* __restrict__ emb,
    const float* __restrict__ Wa, const float* __restrict__ ba,
    const float* __restrict__ Wv, const float* __restrict__ bv,
    float* __restrict__ out)
{
    __shared__ float ee_s[KCODES];
    const int tid = threadIdx.x;
    const int row = blockIdx.x * 256 + tid;

#pragma unroll
    for (int kk = 0; kk < 2; ++kk) {
        int k = tid + 256 * kk;
        const float* e = emb + k * HDIM;
        float a0 = 0.f, a1 = 0.f, a2 = 0.f, a3 = 0.f;
#pragma unroll
        for (int j = 0; j < HDIM; j += 4) {
            a0 = fmaf(e[j + 0], e[j + 0], a0);
            a1 = fmaf(e[j + 1], e[j + 1], a1);
            a2 = fmaf(e[j + 2], e[j + 2], a2);
            a3 = fmaf(e[j + 3], e[j + 3], a3);
        }
        ee_s[k] = (a0 + a1) + (a2 + a3);
    }
    __syncthreads();

    const float4* inr4 = (const float4*)(in + (size_t)row * SDIM);
#define DECLI(n) float4 i##n = inr4[n]; PIN4(i##n)
    R16(DECLI)
#define DECLX(m) float4 x##m = make_float4(bh[4*(m)+0], bh[4*(m)+1], bh[4*(m)+2], bh[4*(m)+3]);
    R32(DECLX)

#define L1N(n) xt = fmaf(i##n.x, wc[(4*(n)+0)*HDIM], xt); xt = fmaf(i##n.y, wc[(4*(n)+1)*HDIM], xt); \
               xt = fmaf(i##n.z, wc[(4*(n)+2)*HDIM], xt); xt = fmaf(i##n.w, wc[(4*(n)+3)*HDIM], xt);
#define L2(m)  x##m.x = fmaf(xt, whr[4*(m)+0], x##m.x); x##m.y = fmaf(xt, whr[4*(m)+1], x##m.y); \
               x##m.z = fmaf(xt, whr[4*(m)+2], x##m.z); x##m.w = fmaf(xt, whr[4*(m)+3], x##m.w);
    for (int t = 0; t < HDIM; ++t) {
        float xt = b1[t];
        const float* wc = W1 + t;
        R16(L1N)
        xt = fmaxf(xt, 0.f);
        const float* whr = Wh + t * HDIM;
        R32(L2)
    }
#define RELUX(m) x##m.x = fmaxf(x##m.x, 0.f); x##m.y = fmaxf(x##m.y, 0.f); \
                 x##m.z = fmaxf(x##m.z, 0.f); x##m.w = fmaxf(x##m.w, 0.f); PIN4(x##m)
    R32(RELUX)

    float v0 = 0.f, v1 = 0.f, v2 = 0.f, v3 = 0.f;
#define VV(m) v0 = fmaf(x##m.x, x##m.x, v0); v1 = fmaf(x##m.y, x##m.y, v1); \
              v2 = fmaf(x##m.z, x##m.z, v2); v3 = fmaf(x##m.w, x##m.w, v3);
    R32(VV)
    const float vv = (v0 + v1) + (v2 + v3);

    float best = FLT_MAX;
    int bi = 0;
#define SC(m) \
    d0 = fmaf(x##m.x, eb[0*HDIM+4*(m)+0], d0); d0 = fmaf(x##m.y, eb[0*HDIM+4*(m)+1], d0); \
    d0 = fmaf(x##m.z, eb[0*HDIM+4*(m)+2], d0); d0 = fmaf(x##m.w, eb[0*HDIM+4*(m)+3], d0); \
    d1 = fmaf(x##m.x, eb[1*HDIM+4*(m)+0], d1); d1 = fmaf(x##m.y, eb[1*HDIM+4*(m)+1], d1); \
    d1 = fmaf(x##m.z, eb[1*HDIM+4*(m)+2], d1); d1 = fmaf(x##m.w, eb[1*HDIM+4*(m)+3], d1); \
    d2 = fmaf(x##m.x, eb[2*HDIM+4*(m)+0], d2); d2 = fmaf(x##m.y, eb[2*HDIM+4*(m)+1], d2); \
    d2 = fmaf(x##m.z, eb[2*HDIM+4*(m)+2], d2); d2 = fmaf(x##m.w, eb[2*HDIM+4*(m)+3], d2); \
    d3 = fmaf(x##m.x, eb[3*HDIM+4*(m)+0], d3); d3 = fmaf(x##m.y, eb[3*HDIM+4*(m)+1], d3); \
    d3 = fmaf(x##m.z, eb[3*HDIM+4*(m)+2], d3); d3 = fmaf(x##m.w, eb[3*HDIM+4*(m)+3], d3); \
    d4 = fmaf(x##m.x, eb[4*HDIM+4*(m)+0], d4); d4 = fmaf(x##m.y, eb[4*HDIM+4*(m)+1], d4); \
    d4 = fmaf(x##m.z, eb[4*HDIM+4*(m)+2], d4); d4 = fmaf(x##m.w, eb[4*HDIM+4*(m)+3], d4); \
    d5 = fmaf(x##m.x, eb[5*HDIM+4*(m)+0], d5); d5 = fmaf(x##m.y, eb[5*HDIM+4*(m)+1], d5); \
    d5 = fmaf(x##m.z, eb[5*HDIM+4*(m)+2], d5); d5 = fmaf(x##m.w, eb[5*HDIM+4*(m)+3], d5); \
    d6 = fmaf(x##m.x, eb[6*HDIM+4*(m)+0], d6); d6 = fmaf(x##m.y, eb[6*HDIM+4*(m)+1], d6); \
    d6 = fmaf(x##m.z, eb[6*HDIM+4*(m)+2], d6); d6 = fmaf(x##m.w, eb[6*HDIM+4*(m)+3], d6); \
    d7 = fmaf(x##m.x, eb[7*HDIM+4*(m)+0], d7); d7 = fmaf(x##m.y, eb[7*HDIM+4*(m)+1], d7); \
    d7 = fmaf(x##m.z, eb[7*HDIM+4*(m)+2], d7); d7 = fmaf(x##m.w, eb[7*HDIM+4*(m)+3], d7);
    for (int k0 = 0; k0 < KCODES; k0 += 8) {
        const float* eb = emb + (size_t)k0 * HDIM;
        float d0 = 0.f, d1 = 0.f, d2 = 0.f, d3 = 0.f;
        float d4 = 0.f, d5 = 0.f, d6 = 0.f, d7 = 0.f;
        R32(SC)
        float dd;
        dd = (vv - 2.f * d0) + ee_s[k0 + 0]; if (dd < best) { best = dd; bi = k0 + 0; }
        dd = (vv - 2.f * d1) + ee_s[k0 + 1]; if (dd < best) { best = dd; bi = k0 + 1; }
        dd = (vv - 2.f * d2) + ee_s[k0 + 2]; if (dd < best) { best = dd; bi = k0 + 2; }
        dd = (vv - 2.f * d3) + ee_s[k0 + 3]; if (dd < best) { best = dd; bi = k0 + 3; }
        dd = (vv - 2.f * d4) + ee_s[k0 + 4]; if (dd < best) { best = dd; bi = k0 + 4; }
        dd = (vv - 2.f * d5) + ee_s[k0 + 5]; if (dd < best) { best = dd; bi = k0 + 5; }
        dd = (vv - 2.f * d6) + ee_s[k0 + 6]; if (dd < best) { best = dd; bi = k0 + 6; }
        dd = (vv - 2.f * d7) + ee_s[k0 + 7]; if (dd < best) { best = dd; bi = k0 + 7; }
    }

    float lg[ADIM];
#pragma unroll
    for (int a = 0; a < ADIM; ++a) lg[a] = ba[a];
    float val = bv[0];
    const float4* q4 = (const float4*)(emb + (size_t)bi * HDIM);
#pragma unroll
    for (int j4 = 0; j4 < HDIM / 4; ++j4) {
        float4 q = q4[j4];
        const int j = 4 * j4;
#pragma unroll
        for (int a = 0; a < ADIM; ++a) {
            float t = lg[a];
            t = fmaf(q.x, Wa[(j + 0) * ADIM + a], t);
            t = fmaf(q.y, Wa[(j + 1) * ADIM + a], t);
            t = fmaf(q.z, Wa[(j + 2) * ADIM + a], t);
            t = fmaf(q.w, Wa[(j + 3) * ADIM + a], t);
            lg[a] = t;
        }
        val = fmaf(q.x, Wv[j + 0], val);
        val = fmaf(q.y, Wv[j + 1], val);
        val = fmaf(q.z, Wv[j + 2], val);
        val = fmaf(q.w, Wv[j + 3], val);
    }
    float m = lg[0];
#pragma unroll
    for (int a = 1; a < ADIM; ++a) m = fmaxf(m, lg[a]);
    float p[ADIM];
    float s = 0.f;
#pragma unroll
    for (int a = 0; a < ADIM; ++a) { p[a] = __expf(lg[a] - m); s += p[a]; }
    const float inv = 1.f / s;
    float4* outp = (float4*)(out + (size_t)row * ADIM);
    outp[0] = make_float4(p[0] * inv, p[1] * inv, p[2] * inv, p[3] * inv);
    outp[1] = make_float4(p[4] * inv, p[5] * inv, p[6] * inv, p[7] * inv);
    out[(size_t)NROWS * ADIM + row] = val;
}

// ===========================================================================
extern "C" void kernel_launch(void* const* d_in, const int* in_sizes, int n_in,
                              void* d_out, int out_size, void* d_ws, size_t ws_size,
                              hipStream_t stream) {
    const float* in  = (const float*)d_in[0];
    const float* W1  = (const float*)d_in[1];
    const float* b1  = (const float*)d_in[2];
    const float* Wh  = (const float*)d_in[3];
    const float* bh  = (const float*)d_in[4];
    const float* emb = (const float*)d_in[5];
    const float* Wa  = (const float*)d_in[6];
    const float* ba  = (const float*)d_in[7];
    const float* Wv  = (const float*)d_in[8];
    const float* bv  = (const float*)d_in[9];
    float* out = (float*)d_out;

    const size_t x2_f = (size_t)NROWS * HDIM;             // 64 MB
    const size_t eT_f = (size_t)KCODES * HDIM;            // 256 KB
    const size_t ee_f = KCODES;                           // 2 KB
    const size_t vv_f = NROWS;                            // 512 KB
    const size_t need = (x2_f + eT_f + ee_f + vv_f) * sizeof(float);

    if (ws_size >= need) {
        float* x2t = (float*)d_ws;
        float* eTp = x2t + x2_f;
        float* eew = eTp + eT_f;
        float* vvs = eew + ee_f;
        prep_e_kernel<<<64, 256, 0, stream>>>(emb, eTp);
        ee_kernel<<<2, 256, 0, stream>>>(emb, eew);
        mlp_kernel<<<NROWS / 64, 256, 0, stream>>>(in, W1, b1, Wh, bh, x2t, vvs, NROWS);
        vq_kernel<<<NROWS / 128, 256, 0, stream>>>(x2t, eTp, eew, vvs, emb,
                                                   Wa, ba, Wv, bv, out, NROWS);
    } else {
        fused_global_kernel<<<NROWS / 256, 256, 0, stream>>>(in, W1, b1, Wh, bh, emb,
                                                             Wa, ba, Wv, bv, out);
    }
}